// Round 1
// baseline (1824.807 us; speedup 1.0000x reference)
//
#include <hip/hip_runtime.h>
#include <math.h>

#define EPSN 1e-12f

// ---------------------------------------------------------------------------
// Tiled fp32 NT GEMM: C[m][n] = sum_k A[m][k] * B[n][k]
// 64x64 block tile, 16x16 threads, 4x4 micro-tile, BK=32, K-transposed LDS.
// ---------------------------------------------------------------------------
__global__ __launch_bounds__(256)
void gemm_nt64(const float* __restrict__ A, const float* __restrict__ Bm,
               float* __restrict__ C, int M, int N, int K)
{
    __shared__ float As_t[32][68];
    __shared__ float Bs_t[32][68];
    const int tid = threadIdx.x;
    const int tx = tid & 15, ty = tid >> 4;
    const int brow = blockIdx.y * 64;
    const int bcol = blockIdx.x * 64;

    float acc[4][4] = {};

    for (int k0 = 0; k0 < K; k0 += 32) {
#pragma unroll
        for (int i = 0; i < 2; ++i) {
            int idx = tid + i * 256;        // 0..511
            int r   = idx >> 3;             // row within tile 0..63
            int c4  = idx & 7;              // float4 index within 32-k slab
            float4 va = *reinterpret_cast<const float4*>(&A[(size_t)(brow + r) * K + k0 + c4 * 4]);
            As_t[c4*4+0][r] = va.x; As_t[c4*4+1][r] = va.y;
            As_t[c4*4+2][r] = va.z; As_t[c4*4+3][r] = va.w;
            float4 vb = *reinterpret_cast<const float4*>(&Bm[(size_t)(bcol + r) * K + k0 + c4 * 4]);
            Bs_t[c4*4+0][r] = vb.x; Bs_t[c4*4+1][r] = vb.y;
            Bs_t[c4*4+2][r] = vb.z; Bs_t[c4*4+3][r] = vb.w;
        }
        __syncthreads();
#pragma unroll
        for (int kk = 0; kk < 32; ++kk) {
            const float4 av = *reinterpret_cast<const float4*>(&As_t[kk][ty * 4]);
            const float4 bv = *reinterpret_cast<const float4*>(&Bs_t[kk][tx * 4]);
            const float* ap = reinterpret_cast<const float*>(&av);
            const float* bp = reinterpret_cast<const float*>(&bv);
#pragma unroll
            for (int i = 0; i < 4; ++i) {
                float a = ap[i];
#pragma unroll
                for (int j = 0; j < 4; ++j) acc[i][j] += a * bp[j];
            }
        }
        __syncthreads();
    }
#pragma unroll
    for (int i = 0; i < 4; ++i) {
        float4 v = make_float4(acc[i][0], acc[i][1], acc[i][2], acc[i][3]);
        *reinterpret_cast<float4*>(&C[(size_t)(brow + ty * 4 + i) * N + bcol + tx * 4]) = v;
    }
}

// ---------------------------------------------------------------------------
// In-place row L2 normalize, K assumed multiple of 1024-ish; block = 256 thr.
// ---------------------------------------------------------------------------
__global__ __launch_bounds__(256)
void l2norm_rows(float* __restrict__ X, int K)
{
    const int row = blockIdx.x;
    const int tid = threadIdx.x;
    float4* Xr = reinterpret_cast<float4*>(X + (size_t)row * K);
    const int nv = K / 4;

    float s = 0.f;
    for (int q = tid; q < nv; q += 256) {
        float4 v = Xr[q];
        s += v.x * v.x + v.y * v.y + v.z * v.z + v.w * v.w;
    }
#pragma unroll
    for (int off = 32; off > 0; off >>= 1) s += __shfl_down(s, off);
    __shared__ float red[4];
    __shared__ float scale_sh;
    if ((tid & 63) == 0) red[tid >> 6] = s;
    __syncthreads();
    if (tid == 0) {
        float n = sqrtf(red[0] + red[1] + red[2] + red[3]);
        scale_sh = 1.f / fmaxf(n, EPSN);
    }
    __syncthreads();
    const float sc = scale_sh;
    for (int q = tid; q < nv; q += 256) {
        float4 v = Xr[q];
        v.x *= sc; v.y *= sc; v.z *= sc; v.w *= sc;
        Xr[q] = v;
    }
}

// ---------------------------------------------------------------------------
// Fused: s = fn @ exfn^T (64x64 tiles), a = sign(s)|s|^p, accumulate
// rowsum(|a|) and echo_raw = a @ exR into global accumulators (atomics).
// Grid: (B/64, NCHUNK); each block sweeps N/NCHUNK columns.
// ---------------------------------------------------------------------------
__global__ __launch_bounds__(256)
void fused_s_echo(const float* __restrict__ fn,   // [B][K] normalized
                  const float* __restrict__ exfn, // [N][K] normalized
                  const float* __restrict__ exR,  // [N][64]
                  float* __restrict__ echo,       // [B][64] accum
                  float* __restrict__ rowsum,     // [B] accum
                  const int* __restrict__ p_ptr,
                  int N, int K, int tiles_per_block)
{
    __shared__ float As_t[32][68];
    __shared__ float Bs_t[32][68];
    __shared__ float aS[64][68];
    __shared__ float eS[64][68];
    __shared__ float rs[64];

    const int tid = threadIdx.x;
    const int tx = tid & 15, ty = tid >> 4;
    const int brow = blockIdx.x * 64;
    const int ncol0 = blockIdx.y * tiles_per_block * 64;
    const int p = *p_ptr;

    float acc_e[4][4] = {};
    float rsum[4] = {0.f, 0.f, 0.f, 0.f};

    for (int nt = 0; nt < tiles_per_block; ++nt) {
        const int ncol = ncol0 + nt * 64;

        // ---- s-tile GEMM ----
        float acc_s[4][4] = {};
        for (int k0 = 0; k0 < K; k0 += 32) {
#pragma unroll
            for (int i = 0; i < 2; ++i) {
                int idx = tid + i * 256;
                int r   = idx >> 3;
                int c4  = idx & 7;
                float4 va = *reinterpret_cast<const float4*>(&fn[(size_t)(brow + r) * K + k0 + c4 * 4]);
                As_t[c4*4+0][r] = va.x; As_t[c4*4+1][r] = va.y;
                As_t[c4*4+2][r] = va.z; As_t[c4*4+3][r] = va.w;
                float4 vb = *reinterpret_cast<const float4*>(&exfn[(size_t)(ncol + r) * K + k0 + c4 * 4]);
                Bs_t[c4*4+0][r] = vb.x; Bs_t[c4*4+1][r] = vb.y;
                Bs_t[c4*4+2][r] = vb.z; Bs_t[c4*4+3][r] = vb.w;
            }
            __syncthreads();
#pragma unroll
            for (int kk = 0; kk < 32; ++kk) {
                const float4 av = *reinterpret_cast<const float4*>(&As_t[kk][ty * 4]);
                const float4 bv = *reinterpret_cast<const float4*>(&Bs_t[kk][tx * 4]);
                const float* ap = reinterpret_cast<const float*>(&av);
                const float* bp = reinterpret_cast<const float*>(&bv);
#pragma unroll
                for (int i = 0; i < 4; ++i) {
                    float a = ap[i];
#pragma unroll
                    for (int j = 0; j < 4; ++j) acc_s[i][j] += a * bp[j];
                }
            }
            __syncthreads();
        }

        // ---- power-sign activation into aS, rowsum partials ----
#pragma unroll
        for (int i = 0; i < 4; ++i) {
            float4 arow;
            float* arp = reinterpret_cast<float*>(&arow);
#pragma unroll
            for (int j = 0; j < 4; ++j) {
                float s = acc_s[i][j];
                float av;
                if (p == 3) av = s * s * s;
                else        av = copysignf(powf(fabsf(s), (float)p), s);
                arp[j] = av;
                rsum[i] += fabsf(av);
            }
            *reinterpret_cast<float4*>(&aS[ty * 4 + i][tx * 4]) = arow;
        }

        // ---- stage exR tile ----
#pragma unroll
        for (int i = 0; i < 4; ++i) {
            int f4 = tid + i * 256;        // float4 index 0..1023
            int r  = f4 >> 4;              // 16 float4 per row of 64
            int c4 = (f4 & 15) * 4;
            float4 v = *reinterpret_cast<const float4*>(&exR[(size_t)(ncol + r) * 64 + c4]);
            eS[r][c4 + 0] = v.x; eS[r][c4 + 1] = v.y;
            eS[r][c4 + 2] = v.z; eS[r][c4 + 3] = v.w;
        }
        __syncthreads();

        // ---- echo mini-GEMM: acc_e[i][j] += sum_n aS[row][n] * eS[n][col] ----
#pragma unroll 8
        for (int n = 0; n < 64; ++n) {
            const float4 ev = *reinterpret_cast<const float4*>(&eS[n][tx * 4]);
            const float* ep = reinterpret_cast<const float*>(&ev);
#pragma unroll
            for (int i = 0; i < 4; ++i) {
                float a = aS[ty * 4 + i][n];
#pragma unroll
                for (int j = 0; j < 4; ++j) acc_e[i][j] += a * ep[j];
            }
        }
        __syncthreads();   // protect aS/eS/As_t/Bs_t for next iteration
    }

    // ---- global accumulation ----
#pragma unroll
    for (int i = 0; i < 4; ++i)
#pragma unroll
        for (int j = 0; j < 4; ++j)
            atomicAdd(&echo[(size_t)(brow + ty * 4 + i) * 64 + tx * 4 + j], acc_e[i][j]);

    if (tid < 64) rs[tid] = 0.f;
    __syncthreads();
#pragma unroll
    for (int i = 0; i < 4; ++i) atomicAdd(&rs[ty * 4 + i], rsum[i]);
    __syncthreads();
    if (tid < 64) atomicAdd(&rowsum[brow + tid], rs[tid]);
}

// ---------------------------------------------------------------------------
// Finalize: echo /= max(rowsum,eps); neg_dists = -||echo - class_reps||;
// BCE-with-logits partial sums.  One thread per B-row.
// ---------------------------------------------------------------------------
__global__ __launch_bounds__(256)
void finalize_kernel(const float* __restrict__ echo, const float* __restrict__ rowsum,
                     const float* __restrict__ class_reps,  // [L][C]
                     const float* __restrict__ labels,      // [B][L]
                     float* __restrict__ out,               // [1 + B*L]
                     float* __restrict__ loss_acc,
                     int B, int L, int C)
{
    extern __shared__ float cr[];          // L*C floats
    const int tid = threadIdx.x;
    for (int i = tid; i < L * C; i += 256) cr[i] = class_reps[i];
    __syncthreads();

    const int row = blockIdx.x * 256 + tid;
    float lsum = 0.f;
    if (row < B) {
        const float inv = 1.f / fmaxf(rowsum[row], EPSN);
        float e[64];
        const float4* er = reinterpret_cast<const float4*>(echo + (size_t)row * 64);
#pragma unroll
        for (int q = 0; q < 16; ++q) {
            float4 v = er[q];
            e[q*4+0] = v.x * inv; e[q*4+1] = v.y * inv;
            e[q*4+2] = v.z * inv; e[q*4+3] = v.w * inv;
        }
        for (int l = 0; l < L; ++l) {
            float d = 0.f;
#pragma unroll
            for (int c = 0; c < 64; ++c) {
                float t = e[c] - cr[l * 64 + c];
                d += t * t;
            }
            float x = -sqrtf(d);
            out[1 + (size_t)row * L + l] = x;
            float y = labels[(size_t)row * L + l];
            lsum += fmaxf(x, 0.f) - x * y + log1pf(expf(-fabsf(x)));
        }
    }
#pragma unroll
    for (int off = 32; off > 0; off >>= 1) lsum += __shfl_down(lsum, off);
    __shared__ float red[4];
    if ((tid & 63) == 0) red[tid >> 6] = lsum;
    __syncthreads();
    if (tid == 0) atomicAdd(loss_acc, red[0] + red[1] + red[2] + red[3]);
}

__global__ void write_loss(const float* __restrict__ loss_acc,
                           float* __restrict__ out, float invBL)
{
    out[0] = loss_acc[0] * invBL;
}

// ---------------------------------------------------------------------------
extern "C" void kernel_launch(void* const* d_in, const int* in_sizes, int n_in,
                              void* d_out, int out_size, void* d_ws, size_t ws_size,
                              hipStream_t stream)
{
    const float* features    = (const float*)d_in[0];   // [B][D]
    const float* labels      = (const float*)d_in[1];   // [B][L]
    const float* g_weight    = (const float*)d_in[2];   // [F][D]
    const float* ex_features = (const float*)d_in[3];   // [N][D]
    const float* ex_reps     = (const float*)d_in[4];   // [N][C]
    const float* class_reps  = (const float*)d_in[5];   // [L][C]
    const int*   p_ptr       = (const int*)d_in[6];

    const int D = 1024;
    const int B = in_sizes[0] / D;          // 4096
    const int F = in_sizes[2] / D;          // 1024
    const int N = in_sizes[3] / D;          // 8192
    const int C = in_sizes[4] / N;          // 64
    const int L = in_sizes[5] / C;          // 28

    // workspace layout (bytes)
    char* ws = (char*)d_ws;
    float* f_proj  = (float*)(ws);                                   // B*F
    float* exf     = (float*)(ws + (size_t)B * F * 4);               // N*F
    float* echo    = (float*)(ws + (size_t)(B + N) * F * 4);         // B*C
    float* rsums   = (float*)(ws + (size_t)(B + N) * F * 4 + (size_t)B * C * 4); // B
    float* loss_a  = rsums + B;                                      // 1

    // zero accumulators (echo + rowsum + loss, contiguous)
    hipMemsetAsync(echo, 0, (size_t)(B * C + B + 4) * 4, stream);

    // projections: X @ W^T
    {
        dim3 g1(F / 64, B / 64);
        gemm_nt64<<<g1, 256, 0, stream>>>(features, g_weight, f_proj, B, F, D);
        dim3 g2(F / 64, N / 64);
        gemm_nt64<<<g2, 256, 0, stream>>>(ex_features, g_weight, exf, N, F, D);
    }
    // L2 normalize rows
    l2norm_rows<<<B, 256, 0, stream>>>(f_proj, F);
    l2norm_rows<<<N, 256, 0, stream>>>(exf, F);

    // fused cosine^p + L1-fold + exemplar readout
    {
        const int NCHUNK = 16;                       // blocks along N
        const int tiles_per_block = N / 64 / NCHUNK; // 8
        dim3 g(B / 64, NCHUNK);
        fused_s_echo<<<g, 256, 0, stream>>>(f_proj, exf, ex_reps, echo, rsums,
                                            p_ptr, N, F, tiles_per_block);
    }

    // finalize: neg_dists + loss partials
    {
        dim3 g((B + 255) / 256);
        size_t shb = (size_t)L * C * sizeof(float);
        finalize_kernel<<<g, 256, shb, stream>>>(echo, rsums, class_reps, labels,
                                                 (float*)d_out, loss_a, B, L, C);
    }
    write_loss<<<1, 1, 0, stream>>>(loss_a, (float*)d_out, 1.f / (float)(B * L));
}

// Round 2
// 867.099 us; speedup vs baseline: 2.1045x; 2.1045x over previous
//
#include <hip/hip_runtime.h>
#include <math.h>

#define EPSN 1e-12f

typedef __attribute__((ext_vector_type(8))) short short8;
typedef __attribute__((ext_vector_type(4))) float f32x4;

// Split fp32 into bf16 hi (truncate) + bf16 lo (truncated remainder).
// x ~= hi + lo with |err| <= 2^-16 |x|; scale bias cancels in L1 normalize.
__device__ inline void split_hi_lo(float x, unsigned short& h, unsigned short& l)
{
    unsigned int xb = __float_as_uint(x);
    h = (unsigned short)(xb >> 16);
    float r = x - __uint_as_float(xb & 0xffff0000u);
    l = (unsigned short)(__float_as_uint(r) >> 16);
}

__device__ inline unsigned short f2bf_rne(float x)
{
    unsigned int u = __float_as_uint(x);
    unsigned int r = u + 0x7fffu + ((u >> 16) & 1u);
    return (unsigned short)(r >> 16);
}

// Stage a 128-row x 64-k fp32 slab into hi/lo bf16 LDS planes.
// LDS layout: plane[row][64 bf16] = 128B rows, 16B chunks XOR-swizzled:
// chunk' = chunk ^ (row&7)  (T2-style, makes frag ds_read_b128 conflict-free).
__device__ inline void stage_tile(const float* __restrict__ src, int K, int k0,
                                  unsigned char* hi_plane, unsigned char* lo_plane,
                                  int tid)
{
#pragma unroll
    for (int q = 0; q < 8; ++q) {
        int idx = tid + q * 256;       // 0..2047
        int row = idx >> 4;            // 0..127
        int f4  = idx & 15;            // float4 slot within 64-k slab
        float4 v = *reinterpret_cast<const float4*>(&src[(size_t)row * K + k0 + f4 * 4]);
        unsigned short h[4], l[4];
        split_hi_lo(v.x, h[0], l[0]);
        split_hi_lo(v.y, h[1], l[1]);
        split_hi_lo(v.z, h[2], l[2]);
        split_hi_lo(v.w, h[3], l[3]);
        int byte = row * 128 + (((f4 >> 1) ^ (row & 7)) << 4) + (f4 & 1) * 8;
        *reinterpret_cast<ushort4*>(hi_plane + byte) = make_ushort4(h[0], h[1], h[2], h[3]);
        *reinterpret_cast<ushort4*>(lo_plane + byte) = make_ushort4(l[0], l[1], l[2], l[3]);
    }
}

__device__ inline short8 read_frag(const unsigned char* plane, int row, int chunk)
{
    int byte = row * 128 + ((chunk ^ (row & 7)) << 4);
    return *reinterpret_cast<const short8*>(plane + byte);
}

// ---------------------------------------------------------------------------
// MFMA bf16x3 NT GEMM: C[M][Nn] fp32 = A[M][K] @ W[Nn][K]^T, K=1024.
// 128x128 tile, 4 waves (2x2), per-wave 64x64 via 4x4 16x16x32 frags.
// ---------------------------------------------------------------------------
__global__ __launch_bounds__(256, 2)
void gemm3_nt(const float* __restrict__ A, const float* __restrict__ W,
              float* __restrict__ C, int Nn, int K)
{
    __shared__ __align__(16) unsigned char smem[65536];
    unsigned char* sA_hi = smem;
    unsigned char* sA_lo = smem + 16384;
    unsigned char* sB_hi = smem + 32768;
    unsigned char* sB_lo = smem + 49152;

    const int tid  = threadIdx.x;
    const int lane = tid & 63;
    const int wave = tid >> 6;
    const int wr = wave >> 1, wc = wave & 1;
    const int brow = blockIdx.y * 128;
    const int bcol = blockIdx.x * 128;
    const float* Abase = A + (size_t)brow * K;
    const float* Bbase = W + (size_t)bcol * K;

    f32x4 acc[4][4] = {};

    for (int k0 = 0; k0 < K; k0 += 64) {
        stage_tile(Abase, K, k0, sA_hi, sA_lo, tid);
        stage_tile(Bbase, K, k0, sB_hi, sB_lo, tid);
        __syncthreads();
#pragma unroll
        for (int kk = 0; kk < 2; ++kk) {
            const int ch = kk * 4 + (lane >> 4);
            short8 bh[4], bl[4];
#pragma unroll
            for (int fn = 0; fn < 4; ++fn) {
                int rb = wc * 64 + fn * 16 + (lane & 15);
                bh[fn] = read_frag(sB_hi, rb, ch);
                bl[fn] = read_frag(sB_lo, rb, ch);
            }
#pragma unroll
            for (int fm = 0; fm < 4; ++fm) {
                int ra = wr * 64 + fm * 16 + (lane & 15);
                short8 ah = read_frag(sA_hi, ra, ch);
                short8 al = read_frag(sA_lo, ra, ch);
#pragma unroll
                for (int fn = 0; fn < 4; ++fn) {
                    acc[fm][fn] = __builtin_amdgcn_mfma_f32_16x16x32_bf16(ah, bh[fn], acc[fm][fn], 0, 0, 0);
                    acc[fm][fn] = __builtin_amdgcn_mfma_f32_16x16x32_bf16(ah, bl[fn], acc[fm][fn], 0, 0, 0);
                    acc[fm][fn] = __builtin_amdgcn_mfma_f32_16x16x32_bf16(al, bh[fn], acc[fm][fn], 0, 0, 0);
                }
            }
        }
        __syncthreads();
    }

    // C/D layout: col = lane&15, row = (lane>>4)*4 + reg  [m89/m91 verified]
#pragma unroll
    for (int fm = 0; fm < 4; ++fm)
#pragma unroll
        for (int fn = 0; fn < 4; ++fn)
#pragma unroll
            for (int reg = 0; reg < 4; ++reg) {
                int row = brow + wr * 64 + fm * 16 + (lane >> 4) * 4 + reg;
                int col = bcol + wc * 64 + fn * 16 + (lane & 15);
                C[(size_t)row * Nn + col] = acc[fm][fn][reg];
            }
}

// ---------------------------------------------------------------------------
// In-place row L2 normalize (K = 1024).
// ---------------------------------------------------------------------------
__global__ __launch_bounds__(256)
void l2norm_rows(float* __restrict__ X, int K)
{
    const int row = blockIdx.x;
    const int tid = threadIdx.x;
    float4* Xr = reinterpret_cast<float4*>(X + (size_t)row * K);
    const int nv = K / 4;

    float s = 0.f;
    for (int q = tid; q < nv; q += 256) {
        float4 v = Xr[q];
        s += v.x * v.x + v.y * v.y + v.z * v.z + v.w * v.w;
    }
#pragma unroll
    for (int off = 32; off > 0; off >>= 1) s += __shfl_down(s, off);
    __shared__ float red[4];
    __shared__ float scale_sh;
    if ((tid & 63) == 0) red[tid >> 6] = s;
    __syncthreads();
    if (tid == 0) {
        float n = sqrtf(red[0] + red[1] + red[2] + red[3]);
        scale_sh = 1.f / fmaxf(n, EPSN);
    }
    __syncthreads();
    const float sc = scale_sh;
    for (int q = tid; q < nv; q += 256) {
        float4 v = Xr[q];
        v.x *= sc; v.y *= sc; v.z *= sc; v.w *= sc;
        Xr[q] = v;
    }
}

// ---------------------------------------------------------------------------
// Fused MFMA kernel: s-tile (128x128) = fn @ exfn^T via bf16x3;
// a = sign(s)|s|^p; rowsum(|a|) fp32; echo += a @ exR via single-bf16 MFMA.
// Grid: (B/128, 16); each block sweeps 4 n-tiles.
// ---------------------------------------------------------------------------
__global__ __launch_bounds__(256, 2)
void fused_mfma(const float* __restrict__ fn,   // [B][1024] normalized
                const float* __restrict__ exfn, // [N][1024] normalized
                const float* __restrict__ exR,  // [N][64]
                float* __restrict__ echo,       // [B][64] accum (zeroed)
                float* __restrict__ rowsum,     // [B] accum (zeroed)
                const int* __restrict__ p_ptr,
                int N, int K)
{
    __shared__ __align__(16) unsigned char smem[65536];
    unsigned char* sA_hi = smem;
    unsigned char* sA_lo = smem + 16384;
    unsigned char* sB_hi = smem + 32768;
    unsigned char* sB_lo = smem + 49152;
    // echo-phase overlay (safe: barriers separate the phases)
    unsigned char* aS = smem;            // [128][128] bf16, 256B rows, swizzled
    unsigned char* eT = smem + 32768;    // [64][128] bf16 (exR^T), swizzled

    const int tid  = threadIdx.x;
    const int lane = tid & 63;
    const int wave = tid >> 6;
    const int wr = wave >> 1, wc = wave & 1;
    const int brow  = blockIdx.x * 128;
    const int ncol0 = blockIdx.y * 4 * 128;
    const int p = p_ptr[0];
    const float* Abase = fn + (size_t)brow * K;

    f32x4 acc_e[2][4] = {};
    float rsum[4][4] = {};

    for (int nt = 0; nt < 4; ++nt) {
        const int ncol = ncol0 + nt * 128;
        const float* Bbase = exfn + (size_t)ncol * K;

        // ---- s-tile GEMM (bf16x3) ----
        f32x4 acc[4][4] = {};
        for (int k0 = 0; k0 < K; k0 += 64) {
            stage_tile(Abase, K, k0, sA_hi, sA_lo, tid);
            stage_tile(Bbase, K, k0, sB_hi, sB_lo, tid);
            __syncthreads();
#pragma unroll
            for (int kk = 0; kk < 2; ++kk) {
                const int ch = kk * 4 + (lane >> 4);
                short8 bh[4], bl[4];
#pragma unroll
                for (int fn2 = 0; fn2 < 4; ++fn2) {
                    int rb = wc * 64 + fn2 * 16 + (lane & 15);
                    bh[fn2] = read_frag(sB_hi, rb, ch);
                    bl[fn2] = read_frag(sB_lo, rb, ch);
                }
#pragma unroll
                for (int fm = 0; fm < 4; ++fm) {
                    int ra = wr * 64 + fm * 16 + (lane & 15);
                    short8 ah = read_frag(sA_hi, ra, ch);
                    short8 al = read_frag(sA_lo, ra, ch);
#pragma unroll
                    for (int fn2 = 0; fn2 < 4; ++fn2) {
                        acc[fm][fn2] = __builtin_amdgcn_mfma_f32_16x16x32_bf16(ah, bh[fn2], acc[fm][fn2], 0, 0, 0);
                        acc[fm][fn2] = __builtin_amdgcn_mfma_f32_16x16x32_bf16(ah, bl[fn2], acc[fm][fn2], 0, 0, 0);
                        acc[fm][fn2] = __builtin_amdgcn_mfma_f32_16x16x32_bf16(al, bh[fn2], acc[fm][fn2], 0, 0, 0);
                    }
                }
            }
            __syncthreads();
        }

        // ---- activation -> aS (bf16, swizzled), rowsum partials (fp32) ----
#pragma unroll
        for (int fm = 0; fm < 4; ++fm)
#pragma unroll
            for (int reg = 0; reg < 4; ++reg) {
                int row = wr * 64 + fm * 16 + (lane >> 4) * 4 + reg;
#pragma unroll
                for (int fn2 = 0; fn2 < 4; ++fn2) {
                    int col = wc * 64 + fn2 * 16 + (lane & 15);
                    float s = acc[fm][fn2][reg];
                    float a;
                    if (p == 3) a = s * s * s;
                    else        a = copysignf(powf(fabsf(s), (float)p), s);
                    rsum[fm][reg] += fabsf(a);
                    int byte = row * 256 + (((col >> 3) ^ (row & 7)) << 4) + (col & 7) * 2;
                    *reinterpret_cast<unsigned short*>(aS + byte) = f2bf_rne(a);
                }
            }

        // ---- stage exR^T tile: eT[c][n] bf16, swizzled ----
        {
            int n  = tid >> 1;              // 0..127
            int c0 = (tid & 1) * 32;
            const float* rsrc = exR + (size_t)(ncol + n) * 64 + c0;
#pragma unroll
            for (int j4 = 0; j4 < 8; ++j4) {
                float4 v = *reinterpret_cast<const float4*>(&rsrc[j4 * 4]);
                float vv[4] = {v.x, v.y, v.z, v.w};
#pragma unroll
                for (int jj = 0; jj < 4; ++jj) {
                    int c = c0 + j4 * 4 + jj;
                    int byte = c * 256 + (((n >> 3) ^ (c & 7)) << 4) + (n & 7) * 2;
                    *reinterpret_cast<unsigned short*>(eT + byte) = f2bf_rne(vv[jj]);
                }
            }
        }
        __syncthreads();

        // ---- echo mini-GEMM: acc_e[128 rows][64] += a[128][128] @ exR[128][64]
        // wave owns rows wave*32..+31 (2 m-frags), all 64 cols (4 n-frags)
#pragma unroll
        for (int ks = 0; ks < 4; ++ks) {
            const int ch = ks * 4 + (lane >> 4);
            short8 bfr[4];
#pragma unroll
            for (int fn2 = 0; fn2 < 4; ++fn2) {
                int rc = fn2 * 16 + (lane & 15);
                int byte = rc * 256 + ((ch ^ (rc & 7)) << 4);
                bfr[fn2] = *reinterpret_cast<const short8*>(eT + byte);
            }
#pragma unroll
            for (int fm2 = 0; fm2 < 2; ++fm2) {
                int ra = wave * 32 + fm2 * 16 + (lane & 15);
                int byte = ra * 256 + ((ch ^ (ra & 7)) << 4);
                short8 af = *reinterpret_cast<const short8*>(aS + byte);
#pragma unroll
                for (int fn2 = 0; fn2 < 4; ++fn2)
                    acc_e[fm2][fn2] = __builtin_amdgcn_mfma_f32_16x16x32_bf16(af, bfr[fn2], acc_e[fm2][fn2], 0, 0, 0);
            }
        }
        __syncthreads();   // protect LDS before next n-tile restages
    }

    // ---- global accumulation: echo ----
#pragma unroll
    for (int fm2 = 0; fm2 < 2; ++fm2)
#pragma unroll
        for (int fn2 = 0; fn2 < 4; ++fn2)
#pragma unroll
            for (int reg = 0; reg < 4; ++reg) {
                int row = brow + wave * 32 + fm2 * 16 + (lane >> 4) * 4 + reg;
                int col = fn2 * 16 + (lane & 15);
                atomicAdd(&echo[(size_t)row * 64 + col], acc_e[fm2][fn2][reg]);
            }

    // ---- rowsum: reduce across the 16 lanes sharing a row, then atomic ----
#pragma unroll
    for (int fm = 0; fm < 4; ++fm)
#pragma unroll
        for (int reg = 0; reg < 4; ++reg) {
            float v = rsum[fm][reg];
            v += __shfl_xor(v, 1);
            v += __shfl_xor(v, 2);
            v += __shfl_xor(v, 4);
            v += __shfl_xor(v, 8);
            if ((lane & 15) == 0) {
                int row = brow + wr * 64 + fm * 16 + (lane >> 4) * 4 + reg;
                atomicAdd(&rowsum[row], v);
            }
        }
}

// ---------------------------------------------------------------------------
// Finalize: echo /= max(rowsum,eps); neg_dists = -||echo - class_reps||;
// BCE-with-logits partial sums.
// ---------------------------------------------------------------------------
__global__ __launch_bounds__(256)
void finalize_kernel(const float* __restrict__ echo, const float* __restrict__ rowsum,
                     const float* __restrict__ class_reps,  // [L][C]
                     const float* __restrict__ labels,      // [B][L]
                     float* __restrict__ out,               // [1 + B*L]
                     float* __restrict__ loss_acc,
                     int B, int L, int C)
{
    extern __shared__ float cr[];          // L*C floats
    const int tid = threadIdx.x;
    for (int i = tid; i < L * C; i += 256) cr[i] = class_reps[i];
    __syncthreads();

    const int row = blockIdx.x * 256 + tid;
    float lsum = 0.f;
    if (row < B) {
        const float inv = 1.f / fmaxf(rowsum[row], EPSN);
        float e[64];
        const float4* er = reinterpret_cast<const float4*>(echo + (size_t)row * 64);
#pragma unroll
        for (int q = 0; q < 16; ++q) {
            float4 v = er[q];
            e[q * 4 + 0] = v.x * inv; e[q * 4 + 1] = v.y * inv;
            e[q * 4 + 2] = v.z * inv; e[q * 4 + 3] = v.w * inv;
        }
        for (int l = 0; l < L; ++l) {
            float d = 0.f;
#pragma unroll
            for (int c = 0; c < 64; ++c) {
                float t = e[c] - cr[l * 64 + c];
                d += t * t;
            }
            float x = -sqrtf(d);
            out[1 + (size_t)row * L + l] = x;
            float y = labels[(size_t)row * L + l];
            lsum += fmaxf(x, 0.f) - x * y + log1pf(expf(-fabsf(x)));
        }
    }
#pragma unroll
    for (int off = 32; off > 0; off >>= 1) lsum += __shfl_down(lsum, off);
    __shared__ float red[4];
    if ((tid & 63) == 0) red[tid >> 6] = lsum;
    __syncthreads();
    if (tid == 0) atomicAdd(loss_acc, red[0] + red[1] + red[2] + red[3]);
}

__global__ void write_loss(const float* __restrict__ loss_acc,
                           float* __restrict__ out, float invBL)
{
    out[0] = loss_acc[0] * invBL;
}

// ---------------------------------------------------------------------------
extern "C" void kernel_launch(void* const* d_in, const int* in_sizes, int n_in,
                              void* d_out, int out_size, void* d_ws, size_t ws_size,
                              hipStream_t stream)
{
    const float* features    = (const float*)d_in[0];   // [B][D]
    const float* labels      = (const float*)d_in[1];   // [B][L]
    const float* g_weight    = (const float*)d_in[2];   // [F][D]
    const float* ex_features = (const float*)d_in[3];   // [N][D]
    const float* ex_reps     = (const float*)d_in[4];   // [N][C]
    const float* class_reps  = (const float*)d_in[5];   // [L][C]
    const int*   p_ptr       = (const int*)d_in[6];

    const int D = 1024;
    const int B = in_sizes[0] / D;          // 4096
    const int F = in_sizes[2] / D;          // 1024
    const int N = in_sizes[3] / D;          // 8192
    const int C = in_sizes[4] / N;          // 64
    const int L = in_sizes[5] / C;          // 28

    // workspace layout (same 49 MB footprint as round 1)
    char* ws = (char*)d_ws;
    float* f_proj = (float*)(ws);                                    // B*F
    float* exf    = (float*)(ws + (size_t)B * F * 4);                // N*F
    float* echo   = (float*)(ws + (size_t)(B + N) * F * 4);          // B*C
    float* rsums  = echo + (size_t)B * C;                            // B
    float* loss_a = rsums + B;                                       // 1

    hipMemsetAsync(echo, 0, (size_t)(B * C + B + 4) * 4, stream);

    // projections: X @ W^T  (bf16x3 MFMA)
    {
        dim3 g1(F / 128, B / 128);
        gemm3_nt<<<g1, 256, 0, stream>>>(features, g_weight, f_proj, F, D);
        dim3 g2(F / 128, N / 128);
        gemm3_nt<<<g2, 256, 0, stream>>>(ex_features, g_weight, exf, F, D);
    }
    // L2 normalize rows
    l2norm_rows<<<B, 256, 0, stream>>>(f_proj, F);
    l2norm_rows<<<N, 256, 0, stream>>>(exf, F);

    // fused cosine^p + L1-fold + exemplar readout (MFMA)
    {
        dim3 g(B / 128, 16);
        fused_mfma<<<g, 256, 0, stream>>>(f_proj, exf, ex_reps, echo, rsums,
                                          p_ptr, N, F);
    }

    // finalize: neg_dists + loss
    {
        dim3 g((B + 255) / 256);
        size_t shb = (size_t)L * C * sizeof(float);
        finalize_kernel<<<g, 256, shb, stream>>>(echo, rsums, class_reps, labels,
                                                 (float*)d_out, loss_a, B, L, C);
    }
    write_loss<<<1, 1, 0, stream>>>(loss_a, (float*)d_out, 1.f / (float)(B * L));
}

// Round 5
// 445.582 us; speedup vs baseline: 4.0953x; 1.9460x over previous
//
#include <hip/hip_runtime.h>
#include <math.h>

#define EPSN 1e-12f

typedef __attribute__((ext_vector_type(8))) short short8;
typedef __attribute__((ext_vector_type(4))) float f32x4;

// ---------------------------------------------------------------------------
// helpers
// ---------------------------------------------------------------------------
__device__ __forceinline__ void split_hi_lo(float x, unsigned short& h, unsigned short& l)
{
    unsigned int xb = __float_as_uint(x);
    h = (unsigned short)(xb >> 16);
    float r = x - __uint_as_float(xb & 0xffff0000u);
    l = (unsigned short)(__float_as_uint(r) >> 16);
}

__device__ __forceinline__ unsigned short f2bf_rne(float x)
{
    unsigned int u = __float_as_uint(x);
    unsigned int r = u + 0x7fffu + ((u >> 16) & 1u);
    return (unsigned short)(r >> 16);
}

// async global->LDS, 16B per lane; LDS dest = wave-uniform base + lane*16
__device__ __forceinline__ void gload16(const void* g, void* l)
{
    __builtin_amdgcn_global_load_lds(
        (const __attribute__((address_space(1))) void*)g,
        (__attribute__((address_space(3))) void*)l, 16, 0, 0);
}

// read one 16B bf16 frag from a swizzled 128B-row plane
__device__ __forceinline__ short8 read_frag(const unsigned char* plane, int row, int chunk)
{
    int byte = row * 128 + ((chunk ^ (row & 7)) << 4);
    return *reinterpret_cast<const short8*>(plane + byte);
}

// reg-staged split staging (used only for the A-side of projection GEMMs):
// 128 rows x 64 k fp32 -> hi/lo bf16 planes, XOR-swizzled 16B chunks.
__device__ __forceinline__ void stage_split(const float* __restrict__ src, int K, int k0,
                                            unsigned char* hi_plane, unsigned char* lo_plane,
                                            int tid)
{
#pragma unroll
    for (int q = 0; q < 8; ++q) {
        int idx = tid + q * 256;       // 0..2047
        int row = idx >> 4;            // 0..127
        int f4  = idx & 15;            // float4 slot within 64-k slab
        float4 v = *reinterpret_cast<const float4*>(&src[(size_t)row * K + k0 + f4 * 4]);
        unsigned short h[4], l[4];
        split_hi_lo(v.x, h[0], l[0]);
        split_hi_lo(v.y, h[1], l[1]);
        split_hi_lo(v.z, h[2], l[2]);
        split_hi_lo(v.w, h[3], l[3]);
        int byte = row * 128 + (((f4 >> 1) ^ (row & 7)) << 4) + (f4 & 1) * 8;
        *reinterpret_cast<ushort4*>(hi_plane + byte) = make_ushort4(h[0], h[1], h[2], h[3]);
        *reinterpret_cast<ushort4*>(lo_plane + byte) = make_ushort4(l[0], l[1], l[2], l[3]);
    }
}

// ---------------------------------------------------------------------------
// tiny prep kernels
// ---------------------------------------------------------------------------
// split one fp32 row (1024) into hi/lo bf16 halves (2048 ushorts), out-of-place
__global__ __launch_bounds__(256)
void split_rows(const float* __restrict__ src, unsigned short* __restrict__ dst)
{
    const int row = blockIdx.x, tid = threadIdx.x;
    float4 v = reinterpret_cast<const float4*>(src + (size_t)row * 1024)[tid];
    unsigned short h[4], l[4];
    split_hi_lo(v.x, h[0], l[0]); split_hi_lo(v.y, h[1], l[1]);
    split_hi_lo(v.z, h[2], l[2]); split_hi_lo(v.w, h[3], l[3]);
    unsigned short* R = dst + (size_t)row * 2048;
    *reinterpret_cast<ushort4*>(R + tid * 4)        = make_ushort4(h[0], h[1], h[2], h[3]);
    *reinterpret_cast<ushort4*>(R + 1024 + tid * 4) = make_ushort4(l[0], l[1], l[2], l[3]);
}

// in-place: fp32 row (1024) -> L2-normalized hi/lo bf16 row (2048 ushorts)
__global__ __launch_bounds__(256)
void l2norm_split(float* __restrict__ X)
{
    const int row = blockIdx.x, tid = threadIdx.x;
    float* Xr = X + (size_t)row * 1024;
    float4 v = reinterpret_cast<float4*>(Xr)[tid];
    float s = v.x * v.x + v.y * v.y + v.z * v.z + v.w * v.w;
#pragma unroll
    for (int off = 32; off > 0; off >>= 1) s += __shfl_down(s, off);
    __shared__ float red[4];
    __shared__ float scale_sh;
    if ((tid & 63) == 0) red[tid >> 6] = s;
    __syncthreads();
    if (tid == 0) {
        float n = sqrtf(red[0] + red[1] + red[2] + red[3]);
        scale_sh = 1.f / fmaxf(n, EPSN);
    }
    __syncthreads();                    // also guarantees all reads done before writes
    const float sc = scale_sh;
    v.x *= sc; v.y *= sc; v.z *= sc; v.w *= sc;
    unsigned short h[4], l[4];
    split_hi_lo(v.x, h[0], l[0]); split_hi_lo(v.y, h[1], l[1]);
    split_hi_lo(v.z, h[2], l[2]); split_hi_lo(v.w, h[3], l[3]);
    unsigned short* R = reinterpret_cast<unsigned short*>(Xr);
    *reinterpret_cast<ushort4*>(R + tid * 4)        = make_ushort4(h[0], h[1], h[2], h[3]);
    *reinterpret_cast<ushort4*>(R + 1024 + tid * 4) = make_ushort4(l[0], l[1], l[2], l[3]);
}

// transpose ex_reps [N][64] fp32 -> exT [64][N] bf16
__global__ __launch_bounds__(256)
void transpose_exR(const float* __restrict__ exR, unsigned short* __restrict__ exT, int N)
{
    __shared__ unsigned short sm[64][256];
    const int tid = threadIdx.x;
    const int n0 = blockIdx.x * 256;
    const float4* src = reinterpret_cast<const float4*>(exR + (size_t)(n0 + tid) * 64);
#pragma unroll
    for (int q = 0; q < 16; ++q) {
        float4 v = src[q];
        sm[q * 4 + 0][tid] = f2bf_rne(v.x);
        sm[q * 4 + 1][tid] = f2bf_rne(v.y);
        sm[q * 4 + 2][tid] = f2bf_rne(v.z);
        sm[q * 4 + 3][tid] = f2bf_rne(v.w);
    }
    __syncthreads();
#pragma unroll
    for (int j = 0; j < 32; ++j) {
        int idx = tid + j * 256;        // ushort2 index over 64x128
        int c = idx >> 7, nl2 = idx & 127;
        *reinterpret_cast<ushort2*>(exT + (size_t)c * N + n0 + nl2 * 2) =
            *reinterpret_cast<const ushort2*>(&sm[c][nl2 * 2]);
    }
}

// ---------------------------------------------------------------------------
// Projection GEMM: C[M][F] fp32 = A[M][K] @ W[F][K]^T via bf16x3 MFMA.
// W comes pre-split (async global_load_lds, pre-swizzled source);
// A is split in-kernel (reg-staged). W loads issued first to hide latency.
// ---------------------------------------------------------------------------
__global__ __launch_bounds__(256, 2)
void gemm_w(const float* __restrict__ A, const unsigned short* __restrict__ spW,
            float* __restrict__ C, int Nn, int K)
{
    __shared__ __align__(16) unsigned char smem[65536];
    unsigned char* sA_hi = smem;
    unsigned char* sA_lo = smem + 16384;
    unsigned char* sB_hi = smem + 32768;
    unsigned char* sB_lo = smem + 49152;

    const int tid  = threadIdx.x;
    const int lane = tid & 63;
    const int wave = tid >> 6;
    const int wr = wave >> 1, wc = wave & 1;
    const int brow = blockIdx.y * 128;
    const int bcol = blockIdx.x * 128;
    const float* Abase = A + (size_t)brow * K;
    const char*  Wbase = (const char*)spW + (size_t)bcol * 4096;

    // per-lane pre-swizzled staging offsets (linear LDS <- swizzled source)
    int offW[4];
#pragma unroll
    for (int i = 0; i < 4; ++i) {
        int t = (wave * 4 + i) * 64 + lane;
        int r = t >> 3, c = (t & 7) ^ (r & 7);
        offW[i] = r * 4096 + c * 16;
    }

    f32x4 acc[4][4] = {};

    for (int k0 = 0; k0 < K; k0 += 64) {
        const int k2 = k0 * 2;
#pragma unroll
        for (int i = 0; i < 4; ++i) {
            gload16(Wbase + offW[i] + k2,        sB_hi + (wave * 4 + i) * 1024);
            gload16(Wbase + offW[i] + 2048 + k2, sB_lo + (wave * 4 + i) * 1024);
        }
        stage_split(Abase, K, k0, sA_hi, sA_lo, tid);
        __syncthreads();
#pragma unroll
        for (int kk = 0; kk < 2; ++kk) {
            const int ch = kk * 4 + (lane >> 4);
            short8 bh[4], bl[4];
#pragma unroll
            for (int fn = 0; fn < 4; ++fn) {
                int rb = wc * 64 + fn * 16 + (lane & 15);
                bh[fn] = read_frag(sB_hi, rb, ch);
                bl[fn] = read_frag(sB_lo, rb, ch);
            }
#pragma unroll
            for (int fm = 0; fm < 4; ++fm) {
                int ra = wr * 64 + fm * 16 + (lane & 15);
                short8 ah = read_frag(sA_hi, ra, ch);
                short8 al = read_frag(sA_lo, ra, ch);
#pragma unroll
                for (int fn = 0; fn < 4; ++fn) {
                    acc[fm][fn] = __builtin_amdgcn_mfma_f32_16x16x32_bf16(ah, bh[fn], acc[fm][fn], 0, 0, 0);
                    acc[fm][fn] = __builtin_amdgcn_mfma_f32_16x16x32_bf16(ah, bl[fn], acc[fm][fn], 0, 0, 0);
                    acc[fm][fn] = __builtin_amdgcn_mfma_f32_16x16x32_bf16(al, bh[fn], acc[fm][fn], 0, 0, 0);
                }
            }
        }
        __syncthreads();
    }

#pragma unroll
    for (int fm = 0; fm < 4; ++fm)
#pragma unroll
        for (int fn = 0; fn < 4; ++fn)
#pragma unroll
            for (int reg = 0; reg < 4; ++reg) {
                int row = brow + wr * 64 + fm * 16 + (lane >> 4) * 4 + reg;
                int col = bcol + wc * 64 + fn * 16 + (lane & 15);
                C[(size_t)row * Nn + col] = acc[fm][fn][reg];
            }
}

// ---------------------------------------------------------------------------
// Fused MFMA kernel, fully pre-split inputs, all staging via global_load_lds.
// s-tile (128x128) = fn @ exfn^T (bf16x3); a = sign(s)|s|^p; rowsum fp32;
// echo += a @ exR (single bf16 MFMA, exT async-staged under activation VALU).
// Grid: (B/128, 16); each block sweeps 4 n-tiles. LDS 64KB -> 2 blocks/CU.
// ---------------------------------------------------------------------------
__global__ __launch_bounds__(256, 2)
void fused_mfma2(const unsigned short* __restrict__ spnF,  // [B][2048] hi|lo
                 const unsigned short* __restrict__ spnE,  // [N][2048] hi|lo
                 const unsigned short* __restrict__ exT,   // [64][N] bf16
                 float* __restrict__ echo,                 // [B][64] accum
                 float* __restrict__ rowsum,               // [B] accum
                 const int* __restrict__ p_ptr,
                 int N, int K)
{
    __shared__ __align__(16) unsigned char smem[65536];
    unsigned char* sA_hi = smem;
    unsigned char* sA_lo = smem + 16384;
    unsigned char* sB_hi = smem + 32768;
    unsigned char* sB_lo = smem + 49152;
    unsigned char* aS = smem;            // overlay over A planes (32KB)
    unsigned char* eT = smem + 49152;    // overlay over B_lo plane (16KB)

    const int tid  = threadIdx.x;
    const int lane = tid & 63;
    const int wave = tid >> 6;
    const int wr = wave >> 1, wc = wave & 1;
    const int brow  = blockIdx.x * 128;
    const int ncol0 = blockIdx.y * 4 * 128;
    const int p = p_ptr[0];
    const char* Af  = (const char*)spnF + (size_t)brow * 4096;
    const char* eTb = (const char*)exT;

    // per-lane pre-swizzled staging offsets
    int offA[4], offE[4];
#pragma unroll
    for (int i = 0; i < 4; ++i) {
        int t = (wave * 4 + i) * 64 + lane;
        int r = t >> 3, c = (t & 7) ^ (r & 7);
        offA[i] = r * 4096 + c * 16;
        int cc = t >> 4, chp = t & 15, c2 = chp ^ (cc & 7);
        offE[i] = cc * (2 * N) + c2 * 16;           // byte offset within exT row-major [64][N]
    }

    f32x4 acc_e[2][4] = {};
    float rsum[4][4] = {};

    for (int nt = 0; nt < 4; ++nt) {
        const int ncol = ncol0 + nt * 128;
        const char* Bn = (const char*)spnE + (size_t)ncol * 4096;

        // ---- s-tile GEMM (bf16x3), async staging ----
        f32x4 acc[4][4] = {};
        for (int k0 = 0; k0 < K; k0 += 64) {
            const int k2 = k0 * 2;
#pragma unroll
            for (int i = 0; i < 4; ++i) {
                gload16(Af + offA[i] + k2,        sA_hi + (wave * 4 + i) * 1024);
                gload16(Af + offA[i] + 2048 + k2, sA_lo + (wave * 4 + i) * 1024);
                gload16(Bn + offA[i] + k2,        sB_hi + (wave * 4 + i) * 1024);
                gload16(Bn + offA[i] + 2048 + k2, sB_lo + (wave * 4 + i) * 1024);
            }
            __syncthreads();
#pragma unroll
            for (int kk = 0; kk < 2; ++kk) {
                const int ch = kk * 4 + (lane >> 4);
                short8 bh[4], bl[4];
#pragma unroll
                for (int fn2 = 0; fn2 < 4; ++fn2) {
                    int rb = wc * 64 + fn2 * 16 + (lane & 15);
                    bh[fn2] = read_frag(sB_hi, rb, ch);
                    bl[fn2] = read_frag(sB_lo, rb, ch);
                }
#pragma unroll
                for (int fm = 0; fm < 4; ++fm) {
                    int ra = wr * 64 + fm * 16 + (lane & 15);
                    short8 ah = read_frag(sA_hi, ra, ch);
                    short8 al = read_frag(sA_lo, ra, ch);
#pragma unroll
                    for (int fn2 = 0; fn2 < 4; ++fn2) {
                        acc[fm][fn2] = __builtin_amdgcn_mfma_f32_16x16x32_bf16(ah, bh[fn2], acc[fm][fn2], 0, 0, 0);
                        acc[fm][fn2] = __builtin_amdgcn_mfma_f32_16x16x32_bf16(ah, bl[fn2], acc[fm][fn2], 0, 0, 0);
                        acc[fm][fn2] = __builtin_amdgcn_mfma_f32_16x16x32_bf16(al, bh[fn2], acc[fm][fn2], 0, 0, 0);
                    }
                }
            }
            __syncthreads();
        }

        // ---- issue exT tile async (lands under activation VALU work) ----
#pragma unroll
        for (int i = 0; i < 4; ++i)
            gload16(eTb + offE[i] + ncol * 2, eT + (wave * 4 + i) * 1024);

        // ---- activation -> aS (bf16, swizzled), rowsum partials (fp32) ----
#pragma unroll
        for (int fm = 0; fm < 4; ++fm)
#pragma unroll
            for (int reg = 0; reg < 4; ++reg) {
                int row = wr * 64 + fm * 16 + (lane >> 4) * 4 + reg;
#pragma unroll
                for (int fn2 = 0; fn2 < 4; ++fn2) {
                    int col = wc * 64 + fn2 * 16 + (lane & 15);
                    float s = acc[fm][fn2][reg];
                    float a;
                    if (p == 3) a = s * s * s;
                    else        a = copysignf(powf(fabsf(s), (float)p), s);
                    rsum[fm][reg] += fabsf(a);
                    int byte = row * 256 + (((col >> 3) ^ (row & 7)) << 4) + (col & 7) * 2;
                    *reinterpret_cast<unsigned short*>(aS + byte) = f2bf_rne(a);
                }
            }
        __syncthreads();   // drains aS ds_writes + eT global_load_lds

        // ---- echo mini-GEMM: acc_e += a[128][128] @ exR[128][64] ----
#pragma unroll
        for (int ks = 0; ks < 4; ++ks) {
            const int ch = ks * 4 + (lane >> 4);
            short8 bfr[4];
#pragma unroll
            for (int fn2 = 0; fn2 < 4; ++fn2) {
                int rc = fn2 * 16 + (lane & 15);
                int byte = rc * 256 + ((ch ^ (rc & 7)) << 4);
                bfr[fn2] = *reinterpret_cast<const short8*>(eT + byte);
            }
#pragma unroll
            for (int fm2 = 0; fm2 < 2; ++fm2) {
                int ra = wave * 32 + fm2 * 16 + (lane & 15);
                int byte = ra * 256 + ((ch ^ (ra & 7)) << 4);
                short8 af = *reinterpret_cast<const short8*>(aS + byte);
#pragma unroll
                for (int fn2 = 0; fn2 < 4; ++fn2)
                    acc_e[fm2][fn2] = __builtin_amdgcn_mfma_f32_16x16x32_bf16(af, bfr[fn2], acc_e[fm2][fn2], 0, 0, 0);
            }
        }
        __syncthreads();   // protect overlays before next n-tile restages
    }

    // ---- global accumulation: echo ----
#pragma unroll
    for (int fm2 = 0; fm2 < 2; ++fm2)
#pragma unroll
        for (int fn2 = 0; fn2 < 4; ++fn2)
#pragma unroll
            for (int reg = 0; reg < 4; ++reg) {
                int row = brow + wave * 32 + fm2 * 16 + (lane >> 4) * 4 + reg;
                int col = fn2 * 16 + (lane & 15);
                atomicAdd(&echo[(size_t)row * 64 + col], acc_e[fm2][fn2][reg]);
            }

    // ---- rowsum: reduce across the 16 lanes sharing a row, then atomic ----
#pragma unroll
    for (int fm = 0; fm < 4; ++fm)
#pragma unroll
        for (int reg = 0; reg < 4; ++reg) {
            float v = rsum[fm][reg];
            v += __shfl_xor(v, 1);
            v += __shfl_xor(v, 2);
            v += __shfl_xor(v, 4);
            v += __shfl_xor(v, 8);
            if ((lane & 15) == 0) {
                int row = brow + wr * 64 + fm * 16 + (lane >> 4) * 4 + reg;
                atomicAdd(&rowsum[row], v);
            }
        }
}

// ---------------------------------------------------------------------------
// Finalize: echo /= max(rowsum,eps); neg_dists = -||echo - class_reps||;
// BCE-with-logits partial sums.
// ---------------------------------------------------------------------------
__global__ __launch_bounds__(256)
void finalize_kernel(const float* __restrict__ echo, const float* __restrict__ rowsum,
                     const float* __restrict__ class_reps,  // [L][C]
                     const float* __restrict__ labels,      // [B][L]
                     float* __restrict__ out,               // [1 + B*L]
                     float* __restrict__ loss_acc,
                     int B, int L, int C)
{
    extern __shared__ float cr[];          // L*C floats
    const int tid = threadIdx.x;
    for (int i = tid; i < L * C; i += 256) cr[i] = class_reps[i];
    __syncthreads();

    const int row = blockIdx.x * 256 + tid;
    float lsum = 0.f;
    if (row < B) {
        const float inv = 1.f / fmaxf(rowsum[row], EPSN);
        float e[64];
        const float4* er = reinterpret_cast<const float4*>(echo + (size_t)row * 64);
#pragma unroll
        for (int q = 0; q < 16; ++q) {
            float4 v = er[q];
            e[q * 4 + 0] = v.x * inv; e[q * 4 + 1] = v.y * inv;
            e[q * 4 + 2] = v.z * inv; e[q * 4 + 3] = v.w * inv;
        }
        for (int l = 0; l < L; ++l) {
            float d = 0.f;
#pragma unroll
            for (int c = 0; c < 64; ++c) {
                float t = e[c] - cr[l * 64 + c];
                d += t * t;
            }
            float x = -sqrtf(d);
            out[1 + (size_t)row * L + l] = x;
            float y = labels[(size_t)row * L + l];
            lsum += fmaxf(x, 0.f) - x * y + log1pf(expf(-fabsf(x)));
        }
    }
#pragma unroll
    for (int off = 32; off > 0; off >>= 1) lsum += __shfl_down(lsum, off);
    __shared__ float red[4];
    if ((tid & 63) == 0) red[tid >> 6] = lsum;
    __syncthreads();
    if (tid == 0) atomicAdd(loss_acc, red[0] + red[1] + red[2] + red[3]);
}

__global__ void write_loss(const float* __restrict__ loss_acc,
                           float* __restrict__ out, float invBL)
{
    out[0] = loss_acc[0] * invBL;
}

// ---------------------------------------------------------------------------
extern "C" void kernel_launch(void* const* d_in, const int* in_sizes, int n_in,
                              void* d_out, int out_size, void* d_ws, size_t ws_size,
                              hipStream_t stream)
{
    const float* features    = (const float*)d_in[0];   // [B][D]
    const float* labels      = (const float*)d_in[1];   // [B][L]
    const float* g_weight    = (const float*)d_in[2];   // [F][D]
    const float* ex_features = (const float*)d_in[3];   // [N][D]
    const float* ex_reps     = (const float*)d_in[4];   // [N][C]
    const float* class_reps  = (const float*)d_in[5];   // [L][C]
    const int*   p_ptr       = (const int*)d_in[6];

    const int D = 1024;
    const int B = in_sizes[0] / D;          // 4096
    const int F = in_sizes[2] / D;          // 1024
    const int N = in_sizes[3] / D;          // 8192
    const int C = in_sizes[4] / N;          // 64
    const int L = in_sizes[5] / C;          // 28

    // workspace layout (bytes), ~57 MB total
    char* ws = (char*)d_ws;
    float*          Xf     = (float*)(ws);                            // B rows: fp32 then hi/lo in-place
    float*          Xe     = (float*)(ws + (size_t)B * 4096);         // N rows
    unsigned short* sp_w   = (unsigned short*)(ws + (size_t)(B + N) * 4096);           // F rows hi/lo
    unsigned short* exT    = (unsigned short*)(ws + (size_t)(B + N + F) * 4096);       // [64][N] bf16
    float*          echo   = (float*)(ws + (size_t)(B + N + F) * 4096 + (size_t)64 * N * 2);
    float*          rsums  = echo + (size_t)B * C;
    float*          loss_a = rsums + B;

    hipMemsetAsync(echo, 0, (size_t)(B * C + B + 4) * 4, stream);

    // prep: split W, transpose exR
    split_rows<<<F, 256, 0, stream>>>(g_weight, sp_w);
    transpose_exR<<<N / 256, 256, 0, stream>>>(ex_reps, exT, N);

    // projections: X @ W^T (bf16x3 MFMA, W async pre-split)
    {
        dim3 g1(F / 128, B / 128);
        gemm_w<<<g1, 256, 0, stream>>>(features, sp_w, Xf, F, D);
        dim3 g2(F / 128, N / 128);
        gemm_w<<<g2, 256, 0, stream>>>(ex_features, sp_w, Xe, F, D);
    }
    // L2 normalize + split in-place
    l2norm_split<<<B, 256, 0, stream>>>(Xf);
    l2norm_split<<<N, 256, 0, stream>>>(Xe);

    // fused cosine^p + L1-fold + exemplar readout
    {
        dim3 g(B / 128, 16);
        fused_mfma2<<<g, 256, 0, stream>>>((const unsigned short*)Xf,
                                           (const unsigned short*)Xe,
                                           exT, echo, rsums, p_ptr, N, F);
    }

    // finalize: neg_dists + loss
    {
        dim3 g((B + 255) / 256);
        size_t shb = (size_t)L * C * sizeof(float);
        finalize_kernel<<<g, 256, shb, stream>>>(echo, rsums, class_reps, labels,
                                                 (float*)d_out, loss_a, B, L, C);
    }
    write_loss<<<1, 1, 0, stream>>>(loss_a, (float*)d_out, 1.f / (float)(B * L));
}